// Round 8
// baseline (325.752 us; speedup 1.0000x reference)
//
#include <hip/hip_runtime.h>
#include <hip/hip_bf16.h>

#define NROWS 8192
#define DDIM  512
#define NS    64
#define KK    8
#define HH    240
#define LDT   40     // staging pitch, bf16 elems (32 + 8 pad)
#define SP2   72     // samp pitch, bf16 elems (64 + 8 pad)

typedef __attribute__((ext_vector_type(8))) short bf16x8;
typedef __attribute__((ext_vector_type(4))) float f32x4;
typedef __attribute__((ext_vector_type(2))) float f32x2;

// packed fp32x2 -> bf16x2 (RNE), lowers to v_cvt_pk_bf16_f32
__device__ inline unsigned cvt2u(float a, float b) {
    __hip_bfloat162 h = __float22bfloat162_rn(make_float2(a, b));
    unsigned u;
    __builtin_memcpy(&u, &h, sizeof(u));
    return u;
}

// ---------------------------------------------------------------------------
// Kernel 0: pack W1 (64*240*8 = 122880 f) and Th (64*8*512 = 262144 f) to bf16.
// ---------------------------------------------------------------------------
__global__ __launch_bounds__(256)
void pack_kernel(const float* __restrict__ W1, const float* __restrict__ Th,
                 ushort* __restrict__ W1b, ushort* __restrict__ Thb)
{
    int i = (blockIdx.x * 256 + threadIdx.x) * 4;
    if (i < 122880) {
        float4 v = *(const float4*)(W1 + i);
        *(uint2*)(W1b + i) = make_uint2(cvt2u(v.x, v.y), cvt2u(v.z, v.w));
    } else {
        int j = i - 122880;
        float4 v = *(const float4*)(Th + j);
        *(uint2*)(Thb + j) = make_uint2(cvt2u(v.x, v.y), cvt2u(v.z, v.w));
    }
}

// ---------------------------------------------------------------------------
// Main fused kernel:
//  phase 1: samp64x64 = bf16(rows) @ Thb^T, BK=32, MFMA fp32 acc
//  phase 2: acc (+noise) -> bf16 samp LDS [64 rows][64 (s,k) cols]
//  phase 3: layer-1 MFMA (A=W1 rows=h, B=samp cols=n; b1 in C-init),
//           relu + packed-W3 fma, fused row-reductions:
//           X-blocks -> sumx[s][tile]; Y-blocks -> maxy/sey[s][tile]
//  (b3 cancels exactly between mean_x and LSE_y -> omitted)
// grid = (256, 8): bx 0..127 X / 128..255 Y row-tiles of 64; by = 8 slices.
// block = 256 (4 waves as 2x2 over 64x64). 8 blocks/CU target.
// ---------------------------------------------------------------------------
__global__ __launch_bounds__(256, 8)
void proj_mlp_kernel(const float* __restrict__ X,
                     const float* __restrict__ Y,
                     const float* __restrict__ Xn,
                     const ushort* __restrict__ Thb,
                     const ushort* __restrict__ W1b,
                     const float* __restrict__ b1,
                     const float* __restrict__ W3,
                     const float* __restrict__ sig_p,
                     float* __restrict__ sumx,   // [NS][128]
                     float* __restrict__ maxy,   // [NS][128]
                     float* __restrict__ sey)    // [NS][128]
{
    __shared__ __align__(16) ushort smem[64 * LDT * 2];   // 10240 B
    ushort* aT = smem;                 // [64][LDT]
    ushort* bT = smem + 64 * LDT;      // [64][LDT]
    ushort* sl = smem;                 // samp [64][SP2] = 9216 B (reuse)

    const int tid  = threadIdx.x;
    const int w    = __builtin_amdgcn_readfirstlane(tid >> 6);
    const int lane = tid & 63;
    const int bx   = blockIdx.x;
    const int by   = blockIdx.y;

    const bool isX = (bx < 128);
    const int  bxl = isX ? bx : (bx - 128);
    const float*  srcA = (isX ? X : Y) + (size_t)bxl * 64 * DDIM;
    const ushort* srcB = Thb + (size_t)by * 64 * DDIM;   // [64 rows][512]

    f32x4 acc[2][2];
#pragma unroll
    for (int m = 0; m < 2; ++m)
#pragma unroll
        for (int n = 0; n < 2; ++n) acc[m][n] = (f32x4){0.f, 0.f, 0.f, 0.f};

    const int wr  = (w >> 1) * 32;
    const int wc  = (w & 1) * 32;
    const int r16 = lane & 15;
    const int hi4 = lane >> 4;
    const int offA = (wr + r16) * LDT + hi4 * 8;
    const int offB = (wc + r16) * LDT + hi4 * 8;

    // A: 2 float4/thread (64 rows x 32 f32); B: 1 uint4/thread (64 rows x 32 bf16)
    const int arow0 = tid >> 3,  ac4 = tid & 7;         // + i*32 rows
    const int brow  = tid >> 2,  bh  = tid & 3;         // 4 uint4 per row

    float4 ra[2];
    uint4  rbv;
#pragma unroll
    for (int i = 0; i < 2; ++i)
        ra[i] = *(const float4*)(srcA + (size_t)(arow0 + i * 32) * DDIM + ac4 * 4);
    rbv = *(const uint4*)(srcB + brow * DDIM + bh * 8);

#pragma unroll 1
    for (int kt = 0; kt < DDIM / 32; ++kt) {
        __syncthreads();
#pragma unroll
        for (int i = 0; i < 2; ++i)
            *(uint2*)(aT + (arow0 + i * 32) * LDT + ac4 * 4) =
                make_uint2(cvt2u(ra[i].x, ra[i].y), cvt2u(ra[i].z, ra[i].w));
        *(uint4*)(bT + brow * LDT + bh * 8) = rbv;
        __syncthreads();

        if (kt + 1 < DDIM / 32) {
            const int k0 = (kt + 1) * 32;
#pragma unroll
            for (int i = 0; i < 2; ++i)
                ra[i] = *(const float4*)(srcA + (size_t)(arow0 + i * 32) * DDIM + k0 + ac4 * 4);
            rbv = *(const uint4*)(srcB + brow * DDIM + k0 + bh * 8);
        }

        bf16x8 af[2], bfv[2];
#pragma unroll
        for (int m = 0; m < 2; ++m) af[m] = *(const bf16x8*)(aT + offA + m * 16 * LDT);
#pragma unroll
        for (int n = 0; n < 2; ++n) bfv[n] = *(const bf16x8*)(bT + offB + n * 16 * LDT);
#pragma unroll
        for (int m = 0; m < 2; ++m)
#pragma unroll
            for (int n = 0; n < 2; ++n)
                acc[m][n] = __builtin_amdgcn_mfma_f32_16x16x32_bf16(af[m], bfv[n], acc[m][n], 0, 0, 0);
    }

    // ---- phase 2: acc (+noise) -> bf16 samp LDS -----------------------------
    const float sig = *sig_p;
    const bool addnoise = (sig > 0.f) && isX;
    const int n0g = bxl * 64;

    __syncthreads();
#pragma unroll
    for (int m = 0; m < 2; ++m)
#pragma unroll
        for (int n = 0; n < 2; ++n) {
            const int col  = wc + n * 16 + r16;
            const int rowb = wr + m * 16 + hi4 * 4;
            float v[4];
#pragma unroll
            for (int j = 0; j < 4; ++j) {
                v[j] = acc[m][n][j];
                if (addnoise)
                    v[j] = fmaf(sig, Xn[(size_t)(n0g + rowb + j) * (NS * KK) + by * 64 + col], v[j]);
            }
            unsigned u01 = cvt2u(v[0], v[1]);
            unsigned u23 = cvt2u(v[2], v[3]);
            sl[(rowb + 0) * SP2 + col] = (ushort)u01;
            sl[(rowb + 1) * SP2 + col] = (ushort)(u01 >> 16);
            sl[(rowb + 2) * SP2 + col] = (ushort)u23;
            sl[(rowb + 3) * SP2 + col] = (ushort)(u23 >> 16);
        }
    __syncthreads();

    // ---- phase 3: layer-1 MFMA + fused reductions (2 slices per wave) -------
#pragma unroll 1
    for (int si = 0; si < 2; ++si) {
        const int sloc = w * 2 + si;
        const int s    = by * 8 + sloc;

        bf16x8 bsamp[4];
#pragma unroll
        for (int nt = 0; nt < 4; ++nt) {
            bf16x8 t = {0, 0, 0, 0, 0, 0, 0, 0};
            if (hi4 == 0)
                t = *(const bf16x8*)(sl + (nt * 16 + r16) * SP2 + sloc * 8);
            bsamp[nt] = t;
        }

        const ushort* w1p = W1b + (size_t)s * HH * KK;
        const float*  b1p = b1 + s * HH;
        const float*  w3p = W3 + s * HH;

        f32x2 pn2[4];
#pragma unroll
        for (int nt = 0; nt < 4; ++nt) pn2[nt] = (f32x2){0.f, 0.f};

#pragma unroll 5
        for (int ht = 0; ht < HH / 16; ++ht) {
            bf16x8 aw = {0, 0, 0, 0, 0, 0, 0, 0};
            if (hi4 == 0)
                aw = *(const bf16x8*)(w1p + (ht * 16 + r16) * 8);
            float4 b4 = *(const float4*)(b1p + ht * 16 + hi4 * 4);
            float4 w4 = *(const float4*)(w3p + ht * 16 + hi4 * 4);
            f32x4 z   = (f32x4){b4.x, b4.y, b4.z, b4.w};
            f32x2 w01 = (f32x2){w4.x, w4.y};
            f32x2 w23 = (f32x2){w4.z, w4.w};
            const f32x2 zero2 = (f32x2){0.f, 0.f};
#pragma unroll
            for (int nt = 0; nt < 4; ++nt) {
                f32x4 t = __builtin_amdgcn_mfma_f32_16x16x32_bf16(aw, bsamp[nt], z, 0, 0, 0);
                f32x2 t01 = (f32x2){t[0], t[1]};
                f32x2 t23 = (f32x2){t[2], t[3]};
                t01 = __builtin_elementwise_max(t01, zero2);
                t23 = __builtin_elementwise_max(t23, zero2);
                pn2[nt] = __builtin_elementwise_fma(t01, w01, pn2[nt]);
                pn2[nt] = __builtin_elementwise_fma(t23, w23, pn2[nt]);
            }
        }

        if (isX) {
            float lsum = 0.f;
#pragma unroll
            for (int nt = 0; nt < 4; ++nt) lsum += pn2[nt].x + pn2[nt].y;
#pragma unroll
            for (int off = 1; off < 64; off <<= 1)
                lsum += __shfl_xor(lsum, off);
            if (lane == 0) sumx[s * 128 + bxl] = lsum;
        } else {
            float p[4];
#pragma unroll
            for (int nt = 0; nt < 4; ++nt) {
                f32x2 v = pn2[nt];
                v.x += __shfl_xor(v.x, 16);
                v.y += __shfl_xor(v.y, 16);
                v.x += __shfl_xor(v.x, 32);
                v.y += __shfl_xor(v.y, 32);
                p[nt] = v.x + v.y;
            }
            float M = fmaxf(fmaxf(p[0], p[1]), fmaxf(p[2], p[3]));
            float se = __expf(p[0] - M) + __expf(p[1] - M)
                     + __expf(p[2] - M) + __expf(p[3] - M);
#pragma unroll
            for (int off = 1; off < 16; off <<= 1) {
                float Mo = __shfl_xor(M, off);
                float so = __shfl_xor(se, off);
                float Mm = fmaxf(M, Mo);
                se = se * __expf(M - Mm) + so * __expf(Mo - Mm);
                M = Mm;
            }
            if (lane == 0) {
                maxy[s * 128 + bxl] = M;
                sey[s * 128 + bxl]  = se;
            }
        }
    }
}

// ---------------------------------------------------------------------------
// Final: 256 threads; thread (s, q=tid&3) covers 32 partials; combine via
// shfl, then LDS + wave-0 reduce over 64 slices -> scalar.
// ---------------------------------------------------------------------------
__global__ __launch_bounds__(256)
void final_kernel(const float* __restrict__ sumx,
                  const float* __restrict__ maxy,
                  const float* __restrict__ sey,
                  float* __restrict__ out)
{
    __shared__ float term_s[NS];
    const int tid = threadIdx.x;
    const int s = tid >> 2, q = tid & 3;
    const int base = s * 128 + q * 32;

    float sum = 0.f, M = -3.4e38f;
#pragma unroll 8
    for (int i = 0; i < 32; ++i) {
        sum += sumx[base + i];
        M = fmaxf(M, maxy[base + i]);
    }
    float se = 0.f;
#pragma unroll 8
    for (int i = 0; i < 32; ++i)
        se += sey[base + i] * __expf(maxy[base + i] - M);

#pragma unroll
    for (int off = 1; off < 4; off <<= 1) {
        float Mo = __shfl_xor(M, off);
        float so = __shfl_xor(se, off);
        float su = __shfl_xor(sum, off);
        float Mm = fmaxf(M, Mo);
        se = se * __expf(M - Mm) + so * __expf(Mo - Mm);
        M = Mm;
        sum += su;
    }
    if (q == 0)
        term_s[s] = M + logf(se) - logf((float)NROWS) - sum * (1.0f / (float)NROWS);
    __syncthreads();
    if (tid < 64) {
        float v = term_s[tid];
#pragma unroll
        for (int off = 1; off < 64; off <<= 1) v += __shfl_xor(v, off);
        if (tid == 0) out[0] = v * (1.0f / (float)NS);
    }
}

// ---------------------------------------------------------------------------
extern "C" void kernel_launch(void* const* d_in, const int* in_sizes, int n_in,
                              void* d_out, int out_size, void* d_ws, size_t ws_size,
                              hipStream_t stream)
{
    const float* X   = (const float*)d_in[0];
    const float* Y   = (const float*)d_in[1];
    const float* Xn  = (const float*)d_in[2];
    const float* Th  = (const float*)d_in[3];
    const float* W1  = (const float*)d_in[4];
    const float* b1  = (const float*)d_in[5];
    const float* W3  = (const float*)d_in[6];
    // d_in[7] = b3: cancels exactly between mean_x and LSE_y -> unused
    const float* sig = (const float*)d_in[8];

    ushort* W1b  = (ushort*)d_ws;                     // 122880 bf16
    ushort* Thb  = W1b + 122880;                      // 262144 bf16
    float*  sumx = (float*)(Thb + 262144);
    float*  maxy = sumx + NS * 128;
    float*  sey  = maxy + NS * 128;

    pack_kernel<<<(122880 + 262144) / 1024, 256, 0, stream>>>(W1, Th, W1b, Thb);

    dim3 g1(256, 8, 1);
    proj_mlp_kernel<<<g1, 256, 0, stream>>>(X, Y, Xn, Thb, W1b, b1, W3,
                                            sig, sumx, maxy, sey);
    final_kernel<<<1, 256, 0, stream>>>(sumx, maxy, sey, (float*)d_out);
}

// Round 9
// 207.182 us; speedup vs baseline: 1.5723x; 1.5723x over previous
//
#include <hip/hip_runtime.h>
#include <hip/hip_bf16.h>

#define NROWS 8192
#define DDIM  512
#define NS    64
#define KK    8
#define HH    240
#define LDT   40     // staging pitch, bf16 elems (32 + 8 pad)
#define SP2   72     // samp pitch, bf16 elems (64 + 8 pad)

typedef __attribute__((ext_vector_type(8))) short bf16x8;
typedef __attribute__((ext_vector_type(4))) float f32x4;
typedef __attribute__((ext_vector_type(2))) float f32x2;

// packed fp32x2 -> bf16x2 (RNE), lowers to v_cvt_pk_bf16_f32
__device__ inline unsigned cvt2u(float a, float b) {
    __hip_bfloat162 h = __float22bfloat162_rn(make_float2(a, b));
    unsigned u;
    __builtin_memcpy(&u, &h, sizeof(u));
    return u;
}

// ---------------------------------------------------------------------------
// Kernel 0: pack W1 (64*240*8 = 122880 f) and Th (64*8*512 = 262144 f) to bf16.
// ---------------------------------------------------------------------------
__global__ __launch_bounds__(256)
void pack_kernel(const float* __restrict__ W1, const float* __restrict__ Th,
                 ushort* __restrict__ W1b, ushort* __restrict__ Thb)
{
    int i = (blockIdx.x * 256 + threadIdx.x) * 4;
    if (i < 122880) {
        float4 v = *(const float4*)(W1 + i);
        *(uint2*)(W1b + i) = make_uint2(cvt2u(v.x, v.y), cvt2u(v.z, v.w));
    } else {
        int j = i - 122880;
        float4 v = *(const float4*)(Th + j);
        *(uint2*)(Thb + j) = make_uint2(cvt2u(v.x, v.y), cvt2u(v.z, v.w));
    }
}

// ---------------------------------------------------------------------------
// Main fused kernel:
//  phase 1: samp64x64 = bf16(rows) @ Thb^T, BK=32, MFMA fp32 acc
//  phase 2: acc (+noise) -> bf16 samp LDS [64 rows][64 (s,k) cols]
//  phase 3: layer-1 MFMA (A=W1 rows=h, B=samp cols=n; b1 in C-init),
//           relu + packed-W3 fma, fused row-reductions:
//           X-blocks -> sumx[s][tile]; Y-blocks -> maxy/sey[s][tile]
//  (b3 cancels exactly between mean_x and LSE_y -> omitted)
// grid = (256, 8): bx 0..127 X / 128..255 Y row-tiles of 64; by = 8 slices.
// block = 256 (4 waves as 2x2 over 64x64).
// __launch_bounds__(256, 6): VGPR cap ~85 >= natural ~60-70 -> no spill
// (round 8's (256,8) capped at 64 -> 1.3 GB scratch traffic, 326 us).
// ---------------------------------------------------------------------------
__global__ __launch_bounds__(256, 6)
void proj_mlp_kernel(const float* __restrict__ X,
                     const float* __restrict__ Y,
                     const float* __restrict__ Xn,
                     const ushort* __restrict__ Thb,
                     const ushort* __restrict__ W1b,
                     const float* __restrict__ b1,
                     const float* __restrict__ W3,
                     const float* __restrict__ sig_p,
                     float* __restrict__ sumx,   // [NS][128]
                     float* __restrict__ maxy,   // [NS][128]
                     float* __restrict__ sey)    // [NS][128]
{
    __shared__ __align__(16) ushort smem[64 * LDT * 2];   // 10240 B
    ushort* aT = smem;                 // [64][LDT]
    ushort* bT = smem + 64 * LDT;      // [64][LDT]
    ushort* sl = smem;                 // samp [64][SP2] = 9216 B (reuse)

    const int tid  = threadIdx.x;
    const int w    = __builtin_amdgcn_readfirstlane(tid >> 6);
    const int lane = tid & 63;
    const int bx   = blockIdx.x;
    const int by   = blockIdx.y;

    const bool isX = (bx < 128);
    const int  bxl = isX ? bx : (bx - 128);
    const float*  srcA = (isX ? X : Y) + (size_t)bxl * 64 * DDIM;
    const ushort* srcB = Thb + (size_t)by * 64 * DDIM;   // [64 rows][512]

    f32x4 acc[2][2];
#pragma unroll
    for (int m = 0; m < 2; ++m)
#pragma unroll
        for (int n = 0; n < 2; ++n) acc[m][n] = (f32x4){0.f, 0.f, 0.f, 0.f};

    const int wr  = (w >> 1) * 32;
    const int wc  = (w & 1) * 32;
    const int r16 = lane & 15;
    const int hi4 = lane >> 4;
    const int offA = (wr + r16) * LDT + hi4 * 8;
    const int offB = (wc + r16) * LDT + hi4 * 8;

    // A: 2 float4/thread (64 rows x 32 f32); B: 1 uint4/thread (64 rows x 32 bf16)
    const int arow0 = tid >> 3,  ac4 = tid & 7;         // + i*32 rows
    const int brow  = tid >> 2,  bh  = tid & 3;         // 4 uint4 per row

    float4 ra[2];
    uint4  rbv;
#pragma unroll
    for (int i = 0; i < 2; ++i)
        ra[i] = *(const float4*)(srcA + (size_t)(arow0 + i * 32) * DDIM + ac4 * 4);
    rbv = *(const uint4*)(srcB + brow * DDIM + bh * 8);

#pragma unroll 1
    for (int kt = 0; kt < DDIM / 32; ++kt) {
        __syncthreads();
#pragma unroll
        for (int i = 0; i < 2; ++i)
            *(uint2*)(aT + (arow0 + i * 32) * LDT + ac4 * 4) =
                make_uint2(cvt2u(ra[i].x, ra[i].y), cvt2u(ra[i].z, ra[i].w));
        *(uint4*)(bT + brow * LDT + bh * 8) = rbv;
        __syncthreads();

        if (kt + 1 < DDIM / 32) {
            const int k0 = (kt + 1) * 32;
#pragma unroll
            for (int i = 0; i < 2; ++i)
                ra[i] = *(const float4*)(srcA + (size_t)(arow0 + i * 32) * DDIM + k0 + ac4 * 4);
            rbv = *(const uint4*)(srcB + brow * DDIM + k0 + bh * 8);
        }

        bf16x8 af[2], bfv[2];
#pragma unroll
        for (int m = 0; m < 2; ++m) af[m] = *(const bf16x8*)(aT + offA + m * 16 * LDT);
#pragma unroll
        for (int n = 0; n < 2; ++n) bfv[n] = *(const bf16x8*)(bT + offB + n * 16 * LDT);
#pragma unroll
        for (int m = 0; m < 2; ++m)
#pragma unroll
            for (int n = 0; n < 2; ++n)
                acc[m][n] = __builtin_amdgcn_mfma_f32_16x16x32_bf16(af[m], bfv[n], acc[m][n], 0, 0, 0);
    }

    // ---- phase 2: acc (+noise) -> bf16 samp LDS -----------------------------
    const float sig = *sig_p;
    const bool addnoise = (sig > 0.f) && isX;
    const int n0g = bxl * 64;

    __syncthreads();
#pragma unroll
    for (int m = 0; m < 2; ++m)
#pragma unroll
        for (int n = 0; n < 2; ++n) {
            const int col  = wc + n * 16 + r16;
            const int rowb = wr + m * 16 + hi4 * 4;
            float v[4];
#pragma unroll
            for (int j = 0; j < 4; ++j) {
                v[j] = acc[m][n][j];
                if (addnoise)
                    v[j] = fmaf(sig, Xn[(size_t)(n0g + rowb + j) * (NS * KK) + by * 64 + col], v[j]);
            }
            unsigned u01 = cvt2u(v[0], v[1]);
            unsigned u23 = cvt2u(v[2], v[3]);
            sl[(rowb + 0) * SP2 + col] = (ushort)u01;
            sl[(rowb + 1) * SP2 + col] = (ushort)(u01 >> 16);
            sl[(rowb + 2) * SP2 + col] = (ushort)u23;
            sl[(rowb + 3) * SP2 + col] = (ushort)(u23 >> 16);
        }
    __syncthreads();

    // ---- phase 3: layer-1 MFMA + fused reductions (2 slices per wave) -------
#pragma unroll 1
    for (int si = 0; si < 2; ++si) {
        const int sloc = w * 2 + si;
        const int s    = by * 8 + sloc;

        bf16x8 bsamp[4];
#pragma unroll
        for (int nt = 0; nt < 4; ++nt) {
            bf16x8 t = {0, 0, 0, 0, 0, 0, 0, 0};
            if (hi4 == 0)
                t = *(const bf16x8*)(sl + (nt * 16 + r16) * SP2 + sloc * 8);
            bsamp[nt] = t;
        }

        const ushort* w1p = W1b + (size_t)s * HH * KK;
        const float*  b1p = b1 + s * HH;
        const float*  w3p = W3 + s * HH;

        f32x2 pn2[4];
#pragma unroll
        for (int nt = 0; nt < 4; ++nt) pn2[nt] = (f32x2){0.f, 0.f};

#pragma unroll 5
        for (int ht = 0; ht < HH / 16; ++ht) {
            bf16x8 aw = {0, 0, 0, 0, 0, 0, 0, 0};
            if (hi4 == 0)
                aw = *(const bf16x8*)(w1p + (ht * 16 + r16) * 8);
            float4 b4 = *(const float4*)(b1p + ht * 16 + hi4 * 4);
            float4 w4 = *(const float4*)(w3p + ht * 16 + hi4 * 4);
            f32x4 z   = (f32x4){b4.x, b4.y, b4.z, b4.w};
            f32x2 w01 = (f32x2){w4.x, w4.y};
            f32x2 w23 = (f32x2){w4.z, w4.w};
            const f32x2 zero2 = (f32x2){0.f, 0.f};
#pragma unroll
            for (int nt = 0; nt < 4; ++nt) {
                f32x4 t = __builtin_amdgcn_mfma_f32_16x16x32_bf16(aw, bsamp[nt], z, 0, 0, 0);
                f32x2 t01 = (f32x2){t[0], t[1]};
                f32x2 t23 = (f32x2){t[2], t[3]};
                t01 = __builtin_elementwise_max(t01, zero2);
                t23 = __builtin_elementwise_max(t23, zero2);
                pn2[nt] = __builtin_elementwise_fma(t01, w01, pn2[nt]);
                pn2[nt] = __builtin_elementwise_fma(t23, w23, pn2[nt]);
            }
        }

        if (isX) {
            float lsum = 0.f;
#pragma unroll
            for (int nt = 0; nt < 4; ++nt) lsum += pn2[nt].x + pn2[nt].y;
#pragma unroll
            for (int off = 1; off < 64; off <<= 1)
                lsum += __shfl_xor(lsum, off);
            if (lane == 0) sumx[s * 128 + bxl] = lsum;
        } else {
            float p[4];
#pragma unroll
            for (int nt = 0; nt < 4; ++nt) {
                f32x2 v = pn2[nt];
                v.x += __shfl_xor(v.x, 16);
                v.y += __shfl_xor(v.y, 16);
                v.x += __shfl_xor(v.x, 32);
                v.y += __shfl_xor(v.y, 32);
                p[nt] = v.x + v.y;
            }
            float M = fmaxf(fmaxf(p[0], p[1]), fmaxf(p[2], p[3]));
            float se = __expf(p[0] - M) + __expf(p[1] - M)
                     + __expf(p[2] - M) + __expf(p[3] - M);
#pragma unroll
            for (int off = 1; off < 16; off <<= 1) {
                float Mo = __shfl_xor(M, off);
                float so = __shfl_xor(se, off);
                float Mm = fmaxf(M, Mo);
                se = se * __expf(M - Mm) + so * __expf(Mo - Mm);
                M = Mm;
            }
            if (lane == 0) {
                maxy[s * 128 + bxl] = M;
                sey[s * 128 + bxl]  = se;
            }
        }
    }
}

// ---------------------------------------------------------------------------
// Final: 256 threads; thread (s, q=tid&3) covers 32 partials; combine via
// shfl, then LDS + wave-0 reduce over 64 slices -> scalar.
// ---------------------------------------------------------------------------
__global__ __launch_bounds__(256)
void final_kernel(const float* __restrict__ sumx,
                  const float* __restrict__ maxy,
                  const float* __restrict__ sey,
                  float* __restrict__ out)
{
    __shared__ float term_s[NS];
    const int tid = threadIdx.x;
    const int s = tid >> 2, q = tid & 3;
    const int base = s * 128 + q * 32;

    float sum = 0.f, M = -3.4e38f;
#pragma unroll 8
    for (int i = 0; i < 32; ++i) {
        sum += sumx[base + i];
        M = fmaxf(M, maxy[base + i]);
    }
    float se = 0.f;
#pragma unroll 8
    for (int i = 0; i < 32; ++i)
        se += sey[base + i] * __expf(maxy[base + i] - M);

#pragma unroll
    for (int off = 1; off < 4; off <<= 1) {
        float Mo = __shfl_xor(M, off);
        float so = __shfl_xor(se, off);
        float su = __shfl_xor(sum, off);
        float Mm = fmaxf(M, Mo);
        se = se * __expf(M - Mm) + so * __expf(Mo - Mm);
        M = Mm;
        sum += su;
    }
    if (q == 0)
        term_s[s] = M + logf(se) - logf((float)NROWS) - sum * (1.0f / (float)NROWS);
    __syncthreads();
    if (tid < 64) {
        float v = term_s[tid];
#pragma unroll
        for (int off = 1; off < 64; off <<= 1) v += __shfl_xor(v, off);
        if (tid == 0) out[0] = v * (1.0f / (float)NS);
    }
}

// ---------------------------------------------------------------------------
extern "C" void kernel_launch(void* const* d_in, const int* in_sizes, int n_in,
                              void* d_out, int out_size, void* d_ws, size_t ws_size,
                              hipStream_t stream)
{
    const float* X   = (const float*)d_in[0];
    const float* Y   = (const float*)d_in[1];
    const float* Xn  = (const float*)d_in[2];
    const float* Th  = (const float*)d_in[3];
    const float* W1  = (const float*)d_in[4];
    const float* b1  = (const float*)d_in[5];
    const float* W3  = (const float*)d_in[6];
    // d_in[7] = b3: cancels exactly between mean_x and LSE_y -> unused
    const float* sig = (const float*)d_in[8];

    ushort* W1b  = (ushort*)d_ws;                     // 122880 bf16
    ushort* Thb  = W1b + 122880;                      // 262144 bf16
    float*  sumx = (float*)(Thb + 262144);
    float*  maxy = sumx + NS * 128;
    float*  sey  = maxy + NS * 128;

    pack_kernel<<<(122880 + 262144) / 1024, 256, 0, stream>>>(W1, Th, W1b, Thb);

    dim3 g1(256, 8, 1);
    proj_mlp_kernel<<<g1, 256, 0, stream>>>(X, Y, Xn, Thb, W1b, b1, W3,
                                            sig, sumx, maxy, sey);
    final_kernel<<<1, 256, 0, stream>>>(sumx, maxy, sey, (float*)d_out);
}

// Round 10
// 68.412 us; speedup vs baseline: 4.7616x; 3.0285x over previous
//
#include <hip/hip_runtime.h>
#include <hip/hip_bf16.h>

#define NROWS 8192
#define DDIM  512
#define NS    64
#define KK    8
#define HH    240
#define LDT   40     // staging pitch, bf16 elems (32 + 8 pad)
#define SP2   72     // samp pitch, bf16 elems (64 + 8 pad)

typedef __attribute__((ext_vector_type(8))) short bf16x8;
typedef __attribute__((ext_vector_type(4))) float f32x4;
typedef __attribute__((ext_vector_type(2))) float f32x2;

// packed fp32x2 -> bf16x2 (RNE), lowers to v_cvt_pk_bf16_f32
__device__ inline unsigned cvt2u(float a, float b) {
    __hip_bfloat162 h = __float22bfloat162_rn(make_float2(a, b));
    unsigned u;
    __builtin_memcpy(&u, &h, sizeof(u));
    return u;
}

// ---------------------------------------------------------------------------
// Kernel 0: pack W1 (64*240*8 = 122880 f) and Th (64*8*512 = 262144 f) to bf16.
// ---------------------------------------------------------------------------
__global__ __launch_bounds__(256)
void pack_kernel(const float* __restrict__ W1, const float* __restrict__ Th,
                 ushort* __restrict__ W1b, ushort* __restrict__ Thb)
{
    int i = (blockIdx.x * 256 + threadIdx.x) * 4;
    if (i < 122880) {
        float4 v = *(const float4*)(W1 + i);
        *(uint2*)(W1b + i) = make_uint2(cvt2u(v.x, v.y), cvt2u(v.z, v.w));
    } else {
        int j = i - 122880;
        float4 v = *(const float4*)(Th + j);
        *(uint2*)(Thb + j) = make_uint2(cvt2u(v.x, v.y), cvt2u(v.z, v.w));
    }
}

// ---------------------------------------------------------------------------
// Main fused kernel:
//  phase 1: samp64x64 = bf16(rows) @ Thb^T, BK=32, MFMA fp32 acc
//  phase 2: acc (+noise) -> bf16 samp LDS [64 rows][64 (s,k) cols]
//  phase 3: layer-1 MFMA (A=W1 rows=h, B=samp cols=n; b1 in C-init),
//           relu + packed-W3 fma, fused row-reductions:
//           X-blocks -> sumx[s][tile]; Y-blocks -> maxy/sey[s][tile]
//  (b3 cancels exactly between mean_x and LSE_y -> omitted)
// grid = (256, 8): bx 0..127 X / 128..255 Y row-tiles of 64; by = 8 slices.
// block = 256 (4 waves as 2x2 over 64x64).
// __launch_bounds__(256, 4): VGPR cap 128 >= natural ~60-70 -> no spill.
// Measured law (r4/5/8/9): k>=6 forces VGPR 32-40 -> 0.4-1.3 GB scratch.
// ---------------------------------------------------------------------------
__global__ __launch_bounds__(256, 4)
void proj_mlp_kernel(const float* __restrict__ X,
                     const float* __restrict__ Y,
                     const float* __restrict__ Xn,
                     const ushort* __restrict__ Thb,
                     const ushort* __restrict__ W1b,
                     const float* __restrict__ b1,
                     const float* __restrict__ W3,
                     const float* __restrict__ sig_p,
                     float* __restrict__ sumx,   // [NS][128]
                     float* __restrict__ maxy,   // [NS][128]
                     float* __restrict__ sey)    // [NS][128]
{
    __shared__ __align__(16) ushort smem[64 * LDT * 2];   // 10240 B
    ushort* aT = smem;                 // [64][LDT]
    ushort* bT = smem + 64 * LDT;      // [64][LDT]
    ushort* sl = smem;                 // samp [64][SP2] = 9216 B (reuse)

    const int tid  = threadIdx.x;
    const int w    = __builtin_amdgcn_readfirstlane(tid >> 6);
    const int lane = tid & 63;
    const int bx   = blockIdx.x;
    const int by   = blockIdx.y;

    const bool isX = (bx < 128);
    const int  bxl = isX ? bx : (bx - 128);
    const float*  srcA = (isX ? X : Y) + (size_t)bxl * 64 * DDIM;
    const ushort* srcB = Thb + (size_t)by * 64 * DDIM;   // [64 rows][512]

    f32x4 acc[2][2];
#pragma unroll
    for (int m = 0; m < 2; ++m)
#pragma unroll
        for (int n = 0; n < 2; ++n) acc[m][n] = (f32x4){0.f, 0.f, 0.f, 0.f};

    const int wr  = (w >> 1) * 32;
    const int wc  = (w & 1) * 32;
    const int r16 = lane & 15;
    const int hi4 = lane >> 4;
    const int offA = (wr + r16) * LDT + hi4 * 8;
    const int offB = (wc + r16) * LDT + hi4 * 8;

    // A: 2 float4/thread (64 rows x 32 f32); B: 1 uint4/thread (64 rows x 32 bf16)
    const int arow0 = tid >> 3,  ac4 = tid & 7;         // + i*32 rows
    const int brow  = tid >> 2,  bh  = tid & 3;         // 4 uint4 per row

    float4 ra[2];
    uint4  rbv;
#pragma unroll
    for (int i = 0; i < 2; ++i)
        ra[i] = *(const float4*)(srcA + (size_t)(arow0 + i * 32) * DDIM + ac4 * 4);
    rbv = *(const uint4*)(srcB + brow * DDIM + bh * 8);

#pragma unroll 1
    for (int kt = 0; kt < DDIM / 32; ++kt) {
        __syncthreads();
#pragma unroll
        for (int i = 0; i < 2; ++i)
            *(uint2*)(aT + (arow0 + i * 32) * LDT + ac4 * 4) =
                make_uint2(cvt2u(ra[i].x, ra[i].y), cvt2u(ra[i].z, ra[i].w));
        *(uint4*)(bT + brow * LDT + bh * 8) = rbv;
        __syncthreads();

        if (kt + 1 < DDIM / 32) {
            const int k0 = (kt + 1) * 32;
#pragma unroll
            for (int i = 0; i < 2; ++i)
                ra[i] = *(const float4*)(srcA + (size_t)(arow0 + i * 32) * DDIM + k0 + ac4 * 4);
            rbv = *(const uint4*)(srcB + brow * DDIM + k0 + bh * 8);
        }

        bf16x8 af[2], bfv[2];
#pragma unroll
        for (int m = 0; m < 2; ++m) af[m] = *(const bf16x8*)(aT + offA + m * 16 * LDT);
#pragma unroll
        for (int n = 0; n < 2; ++n) bfv[n] = *(const bf16x8*)(bT + offB + n * 16 * LDT);
#pragma unroll
        for (int m = 0; m < 2; ++m)
#pragma unroll
            for (int n = 0; n < 2; ++n)
                acc[m][n] = __builtin_amdgcn_mfma_f32_16x16x32_bf16(af[m], bfv[n], acc[m][n], 0, 0, 0);
    }

    // ---- phase 2: acc (+noise) -> bf16 samp LDS -----------------------------
    const float sig = *sig_p;
    const bool addnoise = (sig > 0.f) && isX;
    const int n0g = bxl * 64;

    __syncthreads();
#pragma unroll
    for (int m = 0; m < 2; ++m)
#pragma unroll
        for (int n = 0; n < 2; ++n) {
            const int col  = wc + n * 16 + r16;
            const int rowb = wr + m * 16 + hi4 * 4;
            float v[4];
#pragma unroll
            for (int j = 0; j < 4; ++j) {
                v[j] = acc[m][n][j];
                if (addnoise)
                    v[j] = fmaf(sig, Xn[(size_t)(n0g + rowb + j) * (NS * KK) + by * 64 + col], v[j]);
            }
            unsigned u01 = cvt2u(v[0], v[1]);
            unsigned u23 = cvt2u(v[2], v[3]);
            sl[(rowb + 0) * SP2 + col] = (ushort)u01;
            sl[(rowb + 1) * SP2 + col] = (ushort)(u01 >> 16);
            sl[(rowb + 2) * SP2 + col] = (ushort)u23;
            sl[(rowb + 3) * SP2 + col] = (ushort)(u23 >> 16);
        }
    __syncthreads();

    // ---- phase 3: layer-1 MFMA + fused reductions (2 slices per wave) -------
#pragma unroll 1
    for (int si = 0; si < 2; ++si) {
        const int sloc = w * 2 + si;
        const int s    = by * 8 + sloc;

        bf16x8 bsamp[4];
#pragma unroll
        for (int nt = 0; nt < 4; ++nt) {
            bf16x8 t = {0, 0, 0, 0, 0, 0, 0, 0};
            if (hi4 == 0)
                t = *(const bf16x8*)(sl + (nt * 16 + r16) * SP2 + sloc * 8);
            bsamp[nt] = t;
        }

        const ushort* w1p = W1b + (size_t)s * HH * KK;
        const float*  b1p = b1 + s * HH;
        const float*  w3p = W3 + s * HH;

        f32x2 pn2[4];
#pragma unroll
        for (int nt = 0; nt < 4; ++nt) pn2[nt] = (f32x2){0.f, 0.f};

#pragma unroll 5
        for (int ht = 0; ht < HH / 16; ++ht) {
            bf16x8 aw = {0, 0, 0, 0, 0, 0, 0, 0};
            if (hi4 == 0)
                aw = *(const bf16x8*)(w1p + (ht * 16 + r16) * 8);
            float4 b4 = *(const float4*)(b1p + ht * 16 + hi4 * 4);
            float4 w4 = *(const float4*)(w3p + ht * 16 + hi4 * 4);
            f32x4 z   = (f32x4){b4.x, b4.y, b4.z, b4.w};
            f32x2 w01 = (f32x2){w4.x, w4.y};
            f32x2 w23 = (f32x2){w4.z, w4.w};
            const f32x2 zero2 = (f32x2){0.f, 0.f};
#pragma unroll
            for (int nt = 0; nt < 4; ++nt) {
                f32x4 t = __builtin_amdgcn_mfma_f32_16x16x32_bf16(aw, bsamp[nt], z, 0, 0, 0);
                f32x2 t01 = (f32x2){t[0], t[1]};
                f32x2 t23 = (f32x2){t[2], t[3]};
                t01 = __builtin_elementwise_max(t01, zero2);
                t23 = __builtin_elementwise_max(t23, zero2);
                pn2[nt] = __builtin_elementwise_fma(t01, w01, pn2[nt]);
                pn2[nt] = __builtin_elementwise_fma(t23, w23, pn2[nt]);
            }
        }

        if (isX) {
            float lsum = 0.f;
#pragma unroll
            for (int nt = 0; nt < 4; ++nt) lsum += pn2[nt].x + pn2[nt].y;
#pragma unroll
            for (int off = 1; off < 64; off <<= 1)
                lsum += __shfl_xor(lsum, off);
            if (lane == 0) sumx[s * 128 + bxl] = lsum;
        } else {
            float p[4];
#pragma unroll
            for (int nt = 0; nt < 4; ++nt) {
                f32x2 v = pn2[nt];
                v.x += __shfl_xor(v.x, 16);
                v.y += __shfl_xor(v.y, 16);
                v.x += __shfl_xor(v.x, 32);
                v.y += __shfl_xor(v.y, 32);
                p[nt] = v.x + v.y;
            }
            float M = fmaxf(fmaxf(p[0], p[1]), fmaxf(p[2], p[3]));
            float se = __expf(p[0] - M) + __expf(p[1] - M)
                     + __expf(p[2] - M) + __expf(p[3] - M);
#pragma unroll
            for (int off = 1; off < 16; off <<= 1) {
                float Mo = __shfl_xor(M, off);
                float so = __shfl_xor(se, off);
                float Mm = fmaxf(M, Mo);
                se = se * __expf(M - Mm) + so * __expf(Mo - Mm);
                M = Mm;
            }
            if (lane == 0) {
                maxy[s * 128 + bxl] = M;
                sey[s * 128 + bxl]  = se;
            }
        }
    }
}

// ---------------------------------------------------------------------------
// Final: 256 threads; thread (s, q=tid&3) covers 32 partials; combine via
// shfl, then LDS + wave-0 reduce over 64 slices -> scalar.
// ---------------------------------------------------------------------------
__global__ __launch_bounds__(256)
void final_kernel(const float* __restrict__ sumx,
                  const float* __restrict__ maxy,
                  const float* __restrict__ sey,
                  float* __restrict__ out)
{
    __shared__ float term_s[NS];
    const int tid = threadIdx.x;
    const int s = tid >> 2, q = tid & 3;
    const int base = s * 128 + q * 32;

    float sum = 0.f, M = -3.4e38f;
#pragma unroll 8
    for (int i = 0; i < 32; ++i) {
        sum += sumx[base + i];
        M = fmaxf(M, maxy[base + i]);
    }
    float se = 0.f;
#pragma unroll 8
    for (int i = 0; i < 32; ++i)
        se += sey[base + i] * __expf(maxy[base + i] - M);

#pragma unroll
    for (int off = 1; off < 4; off <<= 1) {
        float Mo = __shfl_xor(M, off);
        float so = __shfl_xor(se, off);
        float su = __shfl_xor(sum, off);
        float Mm = fmaxf(M, Mo);
        se = se * __expf(M - Mm) + so * __expf(Mo - Mm);
        M = Mm;
        sum += su;
    }
    if (q == 0)
        term_s[s] = M + logf(se) - logf((float)NROWS) - sum * (1.0f / (float)NROWS);
    __syncthreads();
    if (tid < 64) {
        float v = term_s[tid];
#pragma unroll
        for (int off = 1; off < 64; off <<= 1) v += __shfl_xor(v, off);
        if (tid == 0) out[0] = v * (1.0f / (float)NS);
    }
}

// ---------------------------------------------------------------------------
extern "C" void kernel_launch(void* const* d_in, const int* in_sizes, int n_in,
                              void* d_out, int out_size, void* d_ws, size_t ws_size,
                              hipStream_t stream)
{
    const float* X   = (const float*)d_in[0];
    const float* Y   = (const float*)d_in[1];
    const float* Xn  = (const float*)d_in[2];
    const float* Th  = (const float*)d_in[3];
    const float* W1  = (const float*)d_in[4];
    const float* b1  = (const float*)d_in[5];
    const float* W3  = (const float*)d_in[6];
    // d_in[7] = b3: cancels exactly between mean_x and LSE_y -> unused
    const float* sig = (const float*)d_in[8];

    ushort* W1b  = (ushort*)d_ws;                     // 122880 bf16
    ushort* Thb  = W1b + 122880;                      // 262144 bf16
    float*  sumx = (float*)(Thb + 262144);
    float*  maxy = sumx + NS * 128;
    float*  sey  = maxy + NS * 128;

    pack_kernel<<<(122880 + 262144) / 1024, 256, 0, stream>>>(W1, Th, W1b, Thb);

    dim3 g1(256, 8, 1);
    proj_mlp_kernel<<<g1, 256, 0, stream>>>(X, Y, Xn, Thb, W1b, b1, W3,
                                            sig, sumx, maxy, sey);
    final_kernel<<<1, 256, 0, stream>>>(sumx, maxy, sey, (float*)d_out);
}